// Round 11
// baseline (308.700 us; speedup 1.0000x reference)
//
#include <hip/hip_runtime.h>
#include <stdint.h>

#define BATCH    16
#define N_VAR    100000
#define N_CLAUSE 400000
#define NR       3
#define RS       33336           // NR*RS = 100008 >= N_VAR; rel fits 16 bits
#define QPB      (N_CLAUSE / 4)  // quads per batch  = 100,000
#define CAP      408000          // bucket capacity: mean 400K, 15-sigma margin

#define TPB_A    512
#define SLOTS    32              // blocks per XCD pair (8*32 = 256 blocks)
#define STRIDE_A (SLOTS * TPB_A) // 16384 quads per iteration per batch
#define NIT      ((QPB + STRIDE_A - 1) / STRIDE_A)   // 7
#define VC       33792           // v-cache floats: 135168 B LDS, 33.8% hit

// dv quantization: |dv| <= 3.2, scale 8192 -> |q| <= 26214 fits int16
#define QSCALE2  8192.0f
#define QINV2    (1.0f / 8192.0f)

typedef int      vi4 __attribute__((ext_vector_type(4)));
typedef float    vf4 __attribute__((ext_vector_type(4)));
typedef uint32_t vu4 __attribute__((ext_vector_type(4)));

__device__ __forceinline__ void do_clause2(
    float g0, float g1, float g2, float s0, float s1, float s2,
    float xlv, float xsv, float amv,
    float& Cv, float& dxlv, float& dxsv,
    float& dv0, float& dv1, float& dv2)
{
    const float a0 = g0 * s0, a1 = g1 * s1, a2 = g2 * s2;
    // top-2 with first-index tie-break (matches jax.lax.top_k)
    const float m = fmaxf(a0, fmaxf(a1, a2));
    const int am = (a0 == m) ? 0 : ((a1 == m) ? 1 : 2);
    const float sec = (am == 0) ? fmaxf(a1, a2)
                    : (am == 1) ? fmaxf(a0, a2)
                                : fmaxf(a0, a1);
    const float C  = 0.5f * (1.0f - m);
    const float t1 = 0.5f * (1.0f - sec);
    const float gam  = t1 * (xlv * xsv) + C * ((1.0f + 0.1f * xlv) * (1.0f - xsv));
    const float goth = C * (xlv * xsv);
    dv0 = -((am == 0) ? gam : goth) * s0;
    dv1 = -((am == 1) ? gam : goth) * s1;
    dv2 = -((am == 2) ? gam : goth) * s2;
    Cv = C;
    const float d = C - 0.05f;   // thresh = DELTA_BY_GAMMA * GAMMA
    dxlv = (C >= 0.05f) ? -(200.0f * amv * d) : -(10.0f * d * (xlv - 1.0f));
    dxsv = -(20.0f * (C - 0.25f));
}

__device__ __forceinline__ void pack2(int gidx, float dv, uint32_t& w, int& r) {
    r = (gidx >= RS) + (gidx >= 2 * RS);
    int q = __float2int_rn(dv * QSCALE2);
    q = max(-32767, min(32767, q));
    w = ((uint32_t)(gidx - r * RS) << 16) | ((uint32_t)q & 0xFFFFu);
}

// -------- Phase A: persistent blocks (1/CU), LDS v-cache serves ~34% of
//          gathers; XCD-pinned batch pairs; bucketed coalesced emission ------
__global__ __launch_bounds__(512) void phaseA_kernel(
    const float* __restrict__ v,
    const int*   __restrict__ idx,
    const float* __restrict__ sgn,
    const float* __restrict__ xl,
    const float* __restrict__ xs,
    const float* __restrict__ amul,
    float*    __restrict__ C_out,
    float*    __restrict__ dxl,
    float*    __restrict__ dxs,
    uint32_t* __restrict__ buckets,
    int*      __restrict__ gcnt)
{
    __shared__ float    vcache[VC];
    __shared__ int      lcnt[3];
    __shared__ int      scan[4];
    __shared__ int      gbase[3];
    __shared__ uint32_t stage[12 * TPB_A];

    const int p    = blockIdx.x & 7;     // XCD pair (round-robin dispatch)
    const int slot = blockIdx.x >> 3;    // 0..31 within pair
    const int tid  = (int)threadIdx.x;

    for (int half = 0; half < 2; ++half) {
        const int b = p * 2 + half;
        const float* __restrict__ vb = v + (size_t)b * N_VAR;

        __syncthreads();   // previous half's gathers done before cache overwrite
        for (int k = tid; k < VC / 4; k += TPB_A)
            ((vf4*)vcache)[k] = ((const vf4*)vb)[k];
        __syncthreads();

        for (int it = 0; it < NIT; ++it) {
            const int q0 = it * STRIDE_A + slot * TPB_A + tid;  // quad in batch
            const bool active = q0 < QPB;
            if (tid < 3) lcnt[tid] = 0;
            __syncthreads();

            uint32_t w0=0,w1=0,w2=0,w3=0,w4=0,w5=0,w6=0,w7=0,w8=0,w9=0,w10=0,w11=0;
            int r0=0,r1=0,r2=0,r3=0,r4=0,r5=0,r6=0,r7=0,r8=0,r9=0,r10=0,r11=0;
            int cA = 0, cB = 0, cC = 0;

            if (active) {
                const int q  = b * QPB + q0;
                const long e = 12L * q;
                const int ci = q * 4;

                // streaming inputs nt: never evict v from the XCD L2
                const vi4 ia = __builtin_nontemporal_load((const vi4*)(idx + e));
                const vi4 ib = __builtin_nontemporal_load((const vi4*)(idx + e + 4));
                const vi4 ic = __builtin_nontemporal_load((const vi4*)(idx + e + 8));
                const vf4 sa = __builtin_nontemporal_load((const vf4*)(sgn + e));
                const vf4 sb = __builtin_nontemporal_load((const vf4*)(sgn + e + 4));
                const vf4 sc = __builtin_nontemporal_load((const vf4*)(sgn + e + 8));
                const vf4 xlv = __builtin_nontemporal_load((const vf4*)(xl + ci));
                const vf4 xsv = __builtin_nontemporal_load((const vf4*)(xs + ci));
                const vf4 amv = __builtin_nontemporal_load((const vf4*)(amul + ci));

                // gather: LDS for idx<VC (exec-masked global only for the rest)
                float g00,g01,g02,g10,g11,g12,g20,g21,g22,g30,g31,g32;
                #define GATH(DST, U) { const int u_ = (U); \
                    if (u_ < VC) DST = vcache[u_]; else DST = vb[u_]; }
                GATH(g00, ia.x) GATH(g01, ia.y) GATH(g02, ia.z)
                GATH(g10, ia.w) GATH(g11, ib.x) GATH(g12, ib.y)
                GATH(g20, ib.z) GATH(g21, ib.w) GATH(g22, ic.x)
                GATH(g30, ic.y) GATH(g31, ic.z) GATH(g32, ic.w)
                #undef GATH

                float C0,C1,C2,C3, L0,L1,L2,L3, S0,S1,S2,S3;
                float d0,d1,d2,d3,d4,d5,d6,d7,d8,d9,d10,d11;
                do_clause2(g00,g01,g02, sa.x,sa.y,sa.z, xlv.x,xsv.x,amv.x, C0,L0,S0, d0,d1,d2);
                do_clause2(g10,g11,g12, sa.w,sb.x,sb.y, xlv.y,xsv.y,amv.y, C1,L1,S1, d3,d4,d5);
                do_clause2(g20,g21,g22, sb.z,sb.w,sc.x, xlv.z,xsv.z,amv.z, C2,L2,S2, d6,d7,d8);
                do_clause2(g30,g31,g32, sc.y,sc.z,sc.w, xlv.w,xsv.w,amv.w, C3,L3,S3, d9,d10,d11);

                vf4 Cv; Cv.x = C0; Cv.y = C1; Cv.z = C2; Cv.w = C3;
                vf4 dl; dl.x = L0; dl.y = L1; dl.z = L2; dl.w = L3;
                vf4 ds; ds.x = S0; ds.y = S1; ds.z = S2; ds.w = S3;
                __builtin_nontemporal_store(Cv, (vf4*)(C_out + ci));
                __builtin_nontemporal_store(dl, (vf4*)(dxl   + ci));
                __builtin_nontemporal_store(ds, (vf4*)(dxs   + ci));

                pack2(ia.x, d0,  w0,  r0);  pack2(ia.y, d1,  w1,  r1);  pack2(ia.z, d2,  w2,  r2);
                pack2(ia.w, d3,  w3,  r3);  pack2(ib.x, d4,  w4,  r4);  pack2(ib.y, d5,  w5,  r5);
                pack2(ib.z, d6,  w6,  r6);  pack2(ib.w, d7,  w7,  r7);  pack2(ic.x, d8,  w8,  r8);
                pack2(ic.y, d9,  w9,  r9);  pack2(ic.z, d10, w10, r10); pack2(ic.w, d11, w11, r11);

                cA = (r0==0)+(r1==0)+(r2==0)+(r3==0)+(r4==0)+(r5==0)
                   + (r6==0)+(r7==0)+(r8==0)+(r9==0)+(r10==0)+(r11==0);
                cB = (r0==1)+(r1==1)+(r2==1)+(r3==1)+(r4==1)+(r5==1)
                   + (r6==1)+(r7==1)+(r8==1)+(r9==1)+(r10==1)+(r11==1);
                cC = 12 - cA - cB;
            }

            int tA = 0, tB = 0, tC = 0;
            if (active) {
                tA = atomicAdd(&lcnt[0], cA);
                tB = atomicAdd(&lcnt[1], cB);
                tC = atomicAdd(&lcnt[2], cC);
            }
            __syncthreads();

            if (tid == 0) {
                scan[0] = 0;
                #pragma unroll
                for (int k = 0; k < 3; ++k) {
                    scan[k + 1] = scan[k] + lcnt[k];
                    gbase[k] = lcnt[k] ? atomicAdd(&gcnt[b * 3 + k], lcnt[k]) : 0;
                }
            }
            __syncthreads();

            if (active) {
                int LA = scan[0] + tA;
                int LB = scan[1] + tB;
                int LC = scan[2] + tC;
                #define EMIT(W, R) { if ((R)==0) stage[LA++] = (W); \
                                     else if ((R)==1) stage[LB++] = (W); \
                                     else stage[LC++] = (W); }
                EMIT(w0,r0)  EMIT(w1,r1)  EMIT(w2,r2)  EMIT(w3,r3)
                EMIT(w4,r4)  EMIT(w5,r5)  EMIT(w6,r6)  EMIT(w7,r7)
                EMIT(w8,r8)  EMIT(w9,r9)  EMIT(w10,r10) EMIT(w11,r11)
                #undef EMIT
            }
            __syncthreads();

            const int tot = scan[3];
            for (int j = tid; j < tot; j += TPB_A) {
                const int k = (j >= scan[1]) + (j >= scan[2]);
                const int dpos = gbase[k] + (j - scan[k]);
                if (dpos < CAP)
                    __builtin_nontemporal_store(stage[j],
                        buckets + (size_t)(b * 3 + k) * CAP + dpos);
            }
            // loop-top barrier (after lcnt reset) separates dump from next stage
        }
    }
}

// -------- Phase B: INTEGER LDS accumulation (ds_add_u32 path), chunked so all
//          256 CUs participate; writes float partials, phase C reduces -------
__global__ __launch_bounds__(1024) void phaseB_kernel(
    const uint32_t* __restrict__ buckets,
    const int*      __restrict__ gcnt,
    float* __restrict__ partial,
    int nC)
{
    __shared__ int acc[RS];

    const int blk = blockIdx.x;
    const int r  = blk % NR;
    const int b2 = (blk / NR) % BATCH;
    const int c  = blk / (NR * BATCH);

    for (int k = threadIdx.x; k < RS; k += 1024) acc[k] = 0;
    __syncthreads();

    int n = gcnt[b2 * 3 + r];
    if (n > CAP) n = CAP;
    const uint32_t* __restrict__ bkt = buckets + (size_t)(b2 * 3 + r) * CAP;
    const int start = (int)(((long)n * c / nC) & ~3L);
    const int end   = (c == nC - 1) ? n : (int)(((long)n * (c + 1) / nC) & ~3L);
    const int len   = end - start;
    const uint32_t* __restrict__ src = bkt + start;

    // integer RMW: atomicAdd(int) -> ds_add_u32 (fast path vs ds_add_f32)
    #define PROC(W) atomicAdd(&acc[(W) >> 16], (int)(short)((W) & 0xFFFFu));
    const int ngrp = len >> 3;               // 8 entries per iteration
    for (int t = threadIdx.x; t < ngrp; t += 1024) {
        const vu4 e0 = __builtin_nontemporal_load((const vu4*)(src + 8 * t));
        const vu4 e1 = __builtin_nontemporal_load((const vu4*)(src + 8 * t + 4));
        PROC(e0.x) PROC(e0.y) PROC(e0.z) PROC(e0.w)
        PROC(e1.x) PROC(e1.y) PROC(e1.z) PROC(e1.w)
    }
    for (int u = (ngrp << 3) + (int)threadIdx.x; u < len; u += 1024) {
        const uint32_t e0 = __builtin_nontemporal_load(src + u);
        PROC(e0)
    }
    #undef PROC
    __syncthreads();

    const int lo = r * RS;
    const int kend = min((int)RS, N_VAR - lo);   // all range ends %4==0
    float* __restrict__ p = partial + ((size_t)c * BATCH + b2) * N_VAR + lo;
    for (int k = threadIdx.x; 4 * k < kend; k += 1024) {
        vf4 f;
        f.x = (float)acc[4 * k + 0] * QINV2;
        f.y = (float)acc[4 * k + 1] * QINV2;
        f.z = (float)acc[4 * k + 2] * QINV2;
        f.w = (float)acc[4 * k + 3] * QINV2;
        __builtin_nontemporal_store(f, (vf4*)(p + 4 * k));
    }
}

// -------- Phase C: reduce per-chunk partials -> vgrad ------------------------
__global__ __launch_bounds__(256) void phaseC_kernel(
    const float* __restrict__ partial,
    float* __restrict__ vgrad,
    int nC)
{
    const int total4 = BATCH * (N_VAR / 4);
    const int t = blockIdx.x * blockDim.x + threadIdx.x;
    if (t >= total4) return;
    const int b  = t / (N_VAR / 4);
    const int k4 = t % (N_VAR / 4);
    vf4 s; s.x = 0.f; s.y = 0.f; s.z = 0.f; s.w = 0.f;
    for (int c = 0; c < nC; ++c) {
        const vf4 p = __builtin_nontemporal_load(
            (const vf4*)&partial[((size_t)c * BATCH + b) * N_VAR + (size_t)k4 * 4]);
        s.x += p.x; s.y += p.y; s.z += p.z; s.w += p.w;
    }
    *(vf4*)&vgrad[(size_t)b * N_VAR + (size_t)k4 * 4] = s;
}

// -------- Fallback: single-pass atomic kernel (if workspace too small) -------
__global__ __launch_bounds__(256) void fallback_kernel(
    const float* __restrict__ v,
    const int*   __restrict__ idx,
    const float* __restrict__ sgn,
    const float* __restrict__ xl,
    const float* __restrict__ xs,
    const float* __restrict__ amul,
    float* __restrict__ C_out,
    float* __restrict__ vgrad,
    float* __restrict__ dxl,
    float* __restrict__ dxs,
    int total)
{
    const int stride = gridDim.x * blockDim.x;
    for (int i = blockIdx.x * blockDim.x + threadIdx.x; i < total; i += stride) {
        const int b = i / N_CLAUSE;
        const long base = 3L * i;
        const int i0 = idx[base], i1 = idx[base + 1], i2 = idx[base + 2];
        const float s0 = sgn[base], s1 = sgn[base + 1], s2 = sgn[base + 2];
        const float* vb = v + (long)b * N_VAR;
        const float a0 = vb[i0] * s0;
        const float a1 = vb[i1] * s1;
        const float a2 = vb[i2] * s2;
        const float m = fmaxf(a0, fmaxf(a1, a2));
        const int am = (a0 == m) ? 0 : ((a1 == m) ? 1 : 2);
        const float sec = (am == 0) ? fmaxf(a1, a2)
                        : (am == 1) ? fmaxf(a0, a2)
                                    : fmaxf(a0, a1);
        const float C  = 0.5f * (1.0f - m);
        const float t1 = 0.5f * (1.0f - sec);
        const float xlv = xl[i];
        const float xsv = xs[i];
        const float gam  = t1 * (xlv * xsv) + C * ((1.0f + 0.1f * xlv) * (1.0f - xsv));
        const float goth = C * (xlv * xsv);
        float* gb = vgrad + (long)b * N_VAR;
        atomicAdd(gb + i0, -((am == 0) ? gam : goth) * s0);
        atomicAdd(gb + i1, -((am == 1) ? gam : goth) * s1);
        atomicAdd(gb + i2, -((am == 2) ? gam : goth) * s2);
        C_out[i] = C;
        const float d = C - 0.05f;
        dxl[i] = (C >= 0.05f) ? -(200.0f * amul[i] * d)
                              : -(10.0f * d * (xlv - 1.0f));
        dxs[i] = -(20.0f * (C - 0.25f));
    }
}

extern "C" void kernel_launch(void* const* d_in, const int* in_sizes, int n_in,
                              void* d_out, int out_size, void* d_ws, size_t ws_size,
                              hipStream_t stream) {
    const float* v    = (const float*)d_in[0];
    const int*   idx  = (const int*)  d_in[1];
    const float* sgn  = (const float*)d_in[2];
    const float* xl   = (const float*)d_in[3];
    const float* xs   = (const float*)d_in[4];
    const float* amul = (const float*)d_in[5];

    float* out   = (float*)d_out;
    float* C_out = out;                                      // 16*400000
    float* vgrad = C_out + (size_t)BATCH * N_CLAUSE;         // 16*100000
    float* dxl   = vgrad + (size_t)BATCH * N_VAR;            // 16*400000
    float* dxs   = dxl   + (size_t)BATCH * N_CLAUSE;         // 16*400000

    const size_t cntBytes = 256;                                  // 48 ints, padded
    const size_t bktBytes = (size_t)BATCH * NR * CAP * 4;         // 78.3 MB
    const size_t perC     = (size_t)BATCH * N_VAR * sizeof(float);// 6.4 MB

    int nC = 0;
    if (ws_size >= cntBytes + bktBytes + perC) {
        const size_t fit = (ws_size - cntBytes - bktBytes) / perC;
        nC = (fit >= 5) ? 5 : (int)fit;    // 5*48 = 240 blocks: all CUs busy
    }

    if (nC >= 1) {
        int*      gcnt    = (int*)d_ws;
        uint32_t* buckets = (uint32_t*)((char*)d_ws + cntBytes);
        float*    partial = (float*)((char*)d_ws + cntBytes + bktBytes);

        (void)hipMemsetAsync(d_ws, 0, cntBytes, stream);   // zero bucket counters

        phaseA_kernel<<<256, TPB_A, 0, stream>>>(
            v, idx, sgn, xl, xs, amul, C_out, dxl, dxs, buckets, gcnt);

        phaseB_kernel<<<nC * BATCH * NR, 1024, 0, stream>>>(buckets, gcnt, partial, nC);

        const int total4 = BATCH * (N_VAR / 4);
        phaseC_kernel<<<(total4 + 255) / 256, 256, 0, stream>>>(partial, vgrad, nC);
    } else {
        (void)hipMemsetAsync(vgrad, 0, sizeof(float) * (size_t)BATCH * N_VAR, stream);
        fallback_kernel<<<2048, 256, 0, stream>>>(v, idx, sgn, xl, xs, amul,
                                                  C_out, vgrad, dxl, dxs,
                                                  BATCH * N_CLAUSE);
    }
}

// Round 12
// 193.141 us; speedup vs baseline: 1.5983x; 1.5983x over previous
//
#include <hip/hip_runtime.h>
#include <stdint.h>

#define BATCH    16
#define N_VAR    100000
#define N_CLAUSE 400000
#define NR       3
#define RS       33336           // NR*RS = 100008 >= N_VAR; rel fits 16 bits
#define QPB      (N_CLAUSE / 4)  // quads per batch  = 100,000
#define QPP      (2 * QPB)       // quads per XCD-pair = 200,000
#define CAP      408000          // bucket capacity: mean 400K, 15-sigma margin

// dv quantization: |dv| <= 3.2, scale 8192 -> |q| <= 26214 fits int16
#define QSCALE2  8192.0f
#define QINV2    (1.0f / 8192.0f)

typedef int      vi4 __attribute__((ext_vector_type(4)));
typedef float    vf4 __attribute__((ext_vector_type(4)));
typedef uint32_t vu4 __attribute__((ext_vector_type(4)));

__device__ __forceinline__ void do_clause2(
    float g0, float g1, float g2, float s0, float s1, float s2,
    float xlv, float xsv, float amv,
    float& Cv, float& dxlv, float& dxsv,
    float& dv0, float& dv1, float& dv2)
{
    const float a0 = g0 * s0, a1 = g1 * s1, a2 = g2 * s2;
    // top-2 with first-index tie-break (matches jax.lax.top_k)
    const float m = fmaxf(a0, fmaxf(a1, a2));
    const int am = (a0 == m) ? 0 : ((a1 == m) ? 1 : 2);
    const float sec = (am == 0) ? fmaxf(a1, a2)
                    : (am == 1) ? fmaxf(a0, a2)
                                : fmaxf(a0, a1);
    const float C  = 0.5f * (1.0f - m);
    const float t1 = 0.5f * (1.0f - sec);
    const float gam  = t1 * (xlv * xsv) + C * ((1.0f + 0.1f * xlv) * (1.0f - xsv));
    const float goth = C * (xlv * xsv);
    dv0 = -((am == 0) ? gam : goth) * s0;
    dv1 = -((am == 1) ? gam : goth) * s1;
    dv2 = -((am == 2) ? gam : goth) * s2;
    Cv = C;
    const float d = C - 0.05f;   // thresh = DELTA_BY_GAMMA * GAMMA
    dxlv = (C >= 0.05f) ? -(200.0f * amv * d) : -(10.0f * d * (xlv - 1.0f));
    dxsv = -(20.0f * (C - 0.25f));
}

__device__ __forceinline__ void pack2(int gidx, float dv, uint32_t& w, int& r) {
    r = (gidx >= RS) + (gidx >= 2 * RS);
    int q = __float2int_rn(dv * QSCALE2);
    q = max(-32767, min(32767, q));
    w = ((uint32_t)(gidx - r * RS) << 16) | ((uint32_t)q & 0xFFFFu);
}

// -------- Phase A: XCD-pinned batches, all-nt streams (protect v in L2),
//          bucketed emission: LDS-staged, block-compacted, coalesced dump ----
__global__ __launch_bounds__(256) void phaseA_kernel(
    const float* __restrict__ v,
    const int*   __restrict__ idx,
    const float* __restrict__ sgn,
    const float* __restrict__ xl,
    const float* __restrict__ xs,
    const float* __restrict__ amul,
    float*    __restrict__ C_out,
    float*    __restrict__ dxl,
    float*    __restrict__ dxs,
    uint32_t* __restrict__ buckets,
    int*      __restrict__ gcnt)
{
    __shared__ int      lcnt[6];     // per local bucket (2 batches x 3 ranges)
    __shared__ int      scan[7];     // exclusive prefix over lcnt
    __shared__ int      gbase[6];    // global reservation per local bucket
    __shared__ uint32_t stage[12 * 256];

    const int p   = blockIdx.x & 7;          // XCD pair id (round-robin dispatch)
    const int inr = blockIdx.x >> 3;
    const int t   = inr * 256 + (int)threadIdx.x;
    const bool active = (t < QPP);

    if (threadIdx.x < 6) lcnt[threadIdx.x] = 0;
    __syncthreads();

    int b = p * 2;
    uint32_t w0=0,w1=0,w2=0,w3=0,w4=0,w5=0,w6=0,w7=0,w8=0,w9=0,w10=0,w11=0;
    int r0=0,r1=0,r2=0,r3=0,r4=0,r5=0,r6=0,r7=0,r8=0,r9=0,r10=0,r11=0;
    int cA = 0, cB = 0, cC = 0;
    int bl = 0;

    if (active) {
        b = p * 2 + t / QPB;
        bl = (b & 1) * 3;
        const int q = b * QPB + t % QPB;
        const long e  = 12L * q;
        const int  ci = q * 4;

        // all streaming inputs nt: never let them evict v from the XCD L2
        const vi4 ia = __builtin_nontemporal_load((const vi4*)(idx + e));
        const vi4 ib = __builtin_nontemporal_load((const vi4*)(idx + e + 4));
        const vi4 ic = __builtin_nontemporal_load((const vi4*)(idx + e + 8));
        const vf4 sa = __builtin_nontemporal_load((const vf4*)(sgn + e));
        const vf4 sb = __builtin_nontemporal_load((const vf4*)(sgn + e + 4));
        const vf4 sc = __builtin_nontemporal_load((const vf4*)(sgn + e + 8));
        const vf4 xlv = __builtin_nontemporal_load((const vf4*)(xl + ci));
        const vf4 xsv = __builtin_nontemporal_load((const vf4*)(xs + ci));
        const vf4 amv = __builtin_nontemporal_load((const vf4*)(amul + ci));

        const float* __restrict__ vb = v + (long)b * N_VAR;
        // 12 independent gathers in flight (cached; v is L2-resident per XCD)
        const float g00 = vb[ia.x], g01 = vb[ia.y], g02 = vb[ia.z];
        const float g10 = vb[ia.w], g11 = vb[ib.x], g12 = vb[ib.y];
        const float g20 = vb[ib.z], g21 = vb[ib.w], g22 = vb[ic.x];
        const float g30 = vb[ic.y], g31 = vb[ic.z], g32 = vb[ic.w];

        float C0,C1,C2,C3, L0,L1,L2,L3, S0,S1,S2,S3;
        float d0,d1,d2,d3,d4,d5,d6,d7,d8,d9,d10,d11;
        do_clause2(g00,g01,g02, sa.x,sa.y,sa.z, xlv.x,xsv.x,amv.x, C0,L0,S0, d0,d1,d2);
        do_clause2(g10,g11,g12, sa.w,sb.x,sb.y, xlv.y,xsv.y,amv.y, C1,L1,S1, d3,d4,d5);
        do_clause2(g20,g21,g22, sb.z,sb.w,sc.x, xlv.z,xsv.z,amv.z, C2,L2,S2, d6,d7,d8);
        do_clause2(g30,g31,g32, sc.y,sc.z,sc.w, xlv.w,xsv.w,amv.w, C3,L3,S3, d9,d10,d11);

        vf4 Cv; Cv.x = C0; Cv.y = C1; Cv.z = C2; Cv.w = C3;
        vf4 dl; dl.x = L0; dl.y = L1; dl.z = L2; dl.w = L3;
        vf4 ds; ds.x = S0; ds.y = S1; ds.z = S2; ds.w = S3;
        __builtin_nontemporal_store(Cv, (vf4*)(C_out + ci));
        __builtin_nontemporal_store(dl, (vf4*)(dxl   + ci));
        __builtin_nontemporal_store(ds, (vf4*)(dxs   + ci));

        pack2(ia.x, d0,  w0,  r0);  pack2(ia.y, d1,  w1,  r1);  pack2(ia.z, d2,  w2,  r2);
        pack2(ia.w, d3,  w3,  r3);  pack2(ib.x, d4,  w4,  r4);  pack2(ib.y, d5,  w5,  r5);
        pack2(ib.z, d6,  w6,  r6);  pack2(ib.w, d7,  w7,  r7);  pack2(ic.x, d8,  w8,  r8);
        pack2(ic.y, d9,  w9,  r9);  pack2(ic.z, d10, w10, r10); pack2(ic.w, d11, w11, r11);

        cA = (r0==0)+(r1==0)+(r2==0)+(r3==0)+(r4==0)+(r5==0)
           + (r6==0)+(r7==0)+(r8==0)+(r9==0)+(r10==0)+(r11==0);
        cB = (r0==1)+(r1==1)+(r2==1)+(r3==1)+(r4==1)+(r5==1)
           + (r6==1)+(r7==1)+(r8==1)+(r9==1)+(r10==1)+(r11==1);
        cC = 12 - cA - cB;
    }

    // block-local reservation
    int tA = 0, tB = 0, tC = 0;
    if (active) {
        tA = atomicAdd(&lcnt[bl + 0], cA);
        tB = atomicAdd(&lcnt[bl + 1], cB);
        tC = atomicAdd(&lcnt[bl + 2], cC);
    }
    __syncthreads();

    if (threadIdx.x == 0) {
        scan[0] = 0;
        #pragma unroll
        for (int k = 0; k < 6; ++k) {
            scan[k + 1] = scan[k] + lcnt[k];
            const int bk = p * 2 + (k >= 3);
            const int rr = k - (k >= 3) * 3;
            gbase[k] = lcnt[k] ? atomicAdd(&gcnt[bk * 3 + rr], lcnt[k]) : 0;
        }
    }
    __syncthreads();

    // stage entries packed by local bucket
    if (active) {
        int LA = scan[bl + 0] + tA;
        int LB = scan[bl + 1] + tB;
        int LC = scan[bl + 2] + tC;
        #define EMIT(W, R) { if ((R)==0) stage[LA++] = (W); \
                             else if ((R)==1) stage[LB++] = (W); \
                             else stage[LC++] = (W); }
        EMIT(w0,r0)  EMIT(w1,r1)  EMIT(w2,r2)  EMIT(w3,r3)
        EMIT(w4,r4)  EMIT(w5,r5)  EMIT(w6,r6)  EMIT(w7,r7)
        EMIT(w8,r8)  EMIT(w9,r9)  EMIT(w10,r10) EMIT(w11,r11)
        #undef EMIT
    }
    __syncthreads();

    // coalesced dump: consecutive stage slots -> consecutive bucket positions
    const int tot = scan[6];
    for (int j = threadIdx.x; j < tot; j += 256) {
        int k = (j >= scan[1]) + (j >= scan[2]) + (j >= scan[3])
              + (j >= scan[4]) + (j >= scan[5]);
        const int bk = p * 2 + (k >= 3);
        const int rr = k - (k >= 3) * 3;
        const int dpos = gbase[k] + (j - scan[k]);
        if (dpos < CAP)
            __builtin_nontemporal_store(stage[j],
                buckets + (size_t)(bk * 3 + rr) * CAP + dpos);
    }
}

// -------- Phase B: INTEGER LDS accumulation (ds_add_u32 path), chunked so all
//          256 CUs participate; writes float partials, phase C reduces -------
__global__ __launch_bounds__(1024) void phaseB_kernel(
    const uint32_t* __restrict__ buckets,
    const int*      __restrict__ gcnt,
    float* __restrict__ partial,
    int nC)
{
    __shared__ int acc[RS];

    const int blk = blockIdx.x;
    const int r  = blk % NR;
    const int b2 = (blk / NR) % BATCH;
    const int c  = blk / (NR * BATCH);

    for (int k = threadIdx.x; k < RS; k += 1024) acc[k] = 0;
    __syncthreads();

    int n = gcnt[b2 * 3 + r];
    if (n > CAP) n = CAP;
    const uint32_t* __restrict__ bkt = buckets + (size_t)(b2 * 3 + r) * CAP;
    const int start = (int)(((long)n * c / nC) & ~3L);
    const int end   = (c == nC - 1) ? n : (int)(((long)n * (c + 1) / nC) & ~3L);
    const int len   = end - start;
    const uint32_t* __restrict__ src = bkt + start;

    // integer RMW: atomicAdd(int) -> ds_add_u32 (fast path vs ds_add_f32)
    #define PROC(W) atomicAdd(&acc[(W) >> 16], (int)(short)((W) & 0xFFFFu));
    const int ngrp = len >> 3;               // 8 entries per iteration
    for (int t = threadIdx.x; t < ngrp; t += 1024) {
        const vu4 e0 = __builtin_nontemporal_load((const vu4*)(src + 8 * t));
        const vu4 e1 = __builtin_nontemporal_load((const vu4*)(src + 8 * t + 4));
        PROC(e0.x) PROC(e0.y) PROC(e0.z) PROC(e0.w)
        PROC(e1.x) PROC(e1.y) PROC(e1.z) PROC(e1.w)
    }
    for (int u = (ngrp << 3) + (int)threadIdx.x; u < len; u += 1024) {
        const uint32_t e0 = __builtin_nontemporal_load(src + u);
        PROC(e0)
    }
    #undef PROC
    __syncthreads();

    const int lo = r * RS;
    const int kend = min((int)RS, N_VAR - lo);   // all range ends %4==0
    float* __restrict__ p = partial + ((size_t)c * BATCH + b2) * N_VAR + lo;
    for (int k = threadIdx.x; 4 * k < kend; k += 1024) {
        vf4 f;
        f.x = (float)acc[4 * k + 0] * QINV2;
        f.y = (float)acc[4 * k + 1] * QINV2;
        f.z = (float)acc[4 * k + 2] * QINV2;
        f.w = (float)acc[4 * k + 3] * QINV2;
        __builtin_nontemporal_store(f, (vf4*)(p + 4 * k));
    }
}

// -------- Phase C: reduce per-chunk partials -> vgrad ------------------------
__global__ __launch_bounds__(256) void phaseC_kernel(
    const float* __restrict__ partial,
    float* __restrict__ vgrad,
    int nC)
{
    const int total4 = BATCH * (N_VAR / 4);
    const int t = blockIdx.x * blockDim.x + threadIdx.x;
    if (t >= total4) return;
    const int b  = t / (N_VAR / 4);
    const int k4 = t % (N_VAR / 4);
    vf4 s; s.x = 0.f; s.y = 0.f; s.z = 0.f; s.w = 0.f;
    for (int c = 0; c < nC; ++c) {
        const vf4 p = __builtin_nontemporal_load(
            (const vf4*)&partial[((size_t)c * BATCH + b) * N_VAR + (size_t)k4 * 4]);
        s.x += p.x; s.y += p.y; s.z += p.z; s.w += p.w;
    }
    *(vf4*)&vgrad[(size_t)b * N_VAR + (size_t)k4 * 4] = s;
}

// -------- Fallback: single-pass atomic kernel (if workspace too small) -------
__global__ __launch_bounds__(256) void fallback_kernel(
    const float* __restrict__ v,
    const int*   __restrict__ idx,
    const float* __restrict__ sgn,
    const float* __restrict__ xl,
    const float* __restrict__ xs,
    const float* __restrict__ amul,
    float* __restrict__ C_out,
    float* __restrict__ vgrad,
    float* __restrict__ dxl,
    float* __restrict__ dxs,
    int total)
{
    const int stride = gridDim.x * blockDim.x;
    for (int i = blockIdx.x * blockDim.x + threadIdx.x; i < total; i += stride) {
        const int b = i / N_CLAUSE;
        const long base = 3L * i;
        const int i0 = idx[base], i1 = idx[base + 1], i2 = idx[base + 2];
        const float s0 = sgn[base], s1 = sgn[base + 1], s2 = sgn[base + 2];
        const float* vb = v + (long)b * N_VAR;
        const float a0 = vb[i0] * s0;
        const float a1 = vb[i1] * s1;
        const float a2 = vb[i2] * s2;
        const float m = fmaxf(a0, fmaxf(a1, a2));
        const int am = (a0 == m) ? 0 : ((a1 == m) ? 1 : 2);
        const float sec = (am == 0) ? fmaxf(a1, a2)
                        : (am == 1) ? fmaxf(a0, a2)
                                    : fmaxf(a0, a1);
        const float C  = 0.5f * (1.0f - m);
        const float t1 = 0.5f * (1.0f - sec);
        const float xlv = xl[i];
        const float xsv = xs[i];
        const float gam  = t1 * (xlv * xsv) + C * ((1.0f + 0.1f * xlv) * (1.0f - xsv));
        const float goth = C * (xlv * xsv);
        float* gb = vgrad + (long)b * N_VAR;
        atomicAdd(gb + i0, -((am == 0) ? gam : goth) * s0);
        atomicAdd(gb + i1, -((am == 1) ? gam : goth) * s1);
        atomicAdd(gb + i2, -((am == 2) ? gam : goth) * s2);
        C_out[i] = C;
        const float d = C - 0.05f;
        dxl[i] = (C >= 0.05f) ? -(200.0f * amul[i] * d)
                              : -(10.0f * d * (xlv - 1.0f));
        dxs[i] = -(20.0f * (C - 0.25f));
    }
}

extern "C" void kernel_launch(void* const* d_in, const int* in_sizes, int n_in,
                              void* d_out, int out_size, void* d_ws, size_t ws_size,
                              hipStream_t stream) {
    const float* v    = (const float*)d_in[0];
    const int*   idx  = (const int*)  d_in[1];
    const float* sgn  = (const float*)d_in[2];
    const float* xl   = (const float*)d_in[3];
    const float* xs   = (const float*)d_in[4];
    const float* amul = (const float*)d_in[5];

    float* out   = (float*)d_out;
    float* C_out = out;                                      // 16*400000
    float* vgrad = C_out + (size_t)BATCH * N_CLAUSE;         // 16*100000
    float* dxl   = vgrad + (size_t)BATCH * N_VAR;            // 16*400000
    float* dxs   = dxl   + (size_t)BATCH * N_CLAUSE;         // 16*400000

    const size_t cntBytes = 256;                                  // 48 ints, padded
    const size_t bktBytes = (size_t)BATCH * NR * CAP * 4;         // 78.3 MB
    const size_t perC     = (size_t)BATCH * N_VAR * sizeof(float);// 6.4 MB

    int nC = 0;
    if (ws_size >= cntBytes + bktBytes + perC) {
        const size_t fit = (ws_size - cntBytes - bktBytes) / perC;
        nC = (fit >= 5) ? 5 : (int)fit;    // 5*48 = 240 blocks: all CUs busy
    }

    if (nC >= 1) {
        int*      gcnt    = (int*)d_ws;
        uint32_t* buckets = (uint32_t*)((char*)d_ws + cntBytes);
        float*    partial = (float*)((char*)d_ws + cntBytes + bktBytes);

        (void)hipMemsetAsync(d_ws, 0, cntBytes, stream);   // zero bucket counters

        const int gridA = 8 * ((QPP + 255) / 256);   // 8 pairs x 782 = 6256
        phaseA_kernel<<<gridA, 256, 0, stream>>>(
            v, idx, sgn, xl, xs, amul, C_out, dxl, dxs, buckets, gcnt);

        phaseB_kernel<<<nC * BATCH * NR, 1024, 0, stream>>>(buckets, gcnt, partial, nC);

        const int total4 = BATCH * (N_VAR / 4);
        phaseC_kernel<<<(total4 + 255) / 256, 256, 0, stream>>>(partial, vgrad, nC);
    } else {
        (void)hipMemsetAsync(vgrad, 0, sizeof(float) * (size_t)BATCH * N_VAR, stream);
        fallback_kernel<<<2048, 256, 0, stream>>>(v, idx, sgn, xl, xs, amul,
                                                  C_out, vgrad, dxl, dxs,
                                                  BATCH * N_CLAUSE);
    }
}